// Round 2
// baseline (757.961 us; speedup 1.0000x reference)
//
#include <hip/hip_runtime.h>
#include <hip/hip_bf16.h>

// NeuralNetwork_85255100825763
// conv1+bn+relu+pool -> conv2+bn+relu+pool -> MLP+softmax gate
// -> 8x LSTM(128) over 256 steps -> gated mean -> output proj.
// LSTM v2: 256 blocks x 1024 threads. Thread owns HALF a gate row
// (16 float4 = 64 VGPRs, guaranteed register-resident), lane-pair
// combines via shfl_xor(1). h/gates via LDS, 2 barriers/step.

__device__ __forceinline__ float sigmoidf_(float x) {
    return 1.0f / (1.0f + __expf(-x));
}
__device__ __forceinline__ float tanhf_(float x) {
    // saturation-safe: exp(-2|x|) in (0,1], no overflow/NaN
    float t = __expf(-2.0f * fabsf(x));
    float r = (1.0f - t) / (1.0f + t);
    return copysignf(r, x);
}

// ---------------- Kernel 1: conv1 + bn1 + relu + maxpool2 -> c1 (64,16,64,64)
__global__ __launch_bounds__(256) void k_conv1(
    const float* __restrict__ x, const float* __restrict__ w,
    const float* __restrict__ cb, const float* __restrict__ g,
    const float* __restrict__ bb, const float* __restrict__ m,
    const float* __restrict__ v, float* __restrict__ c1)
{
    __shared__ __align__(16) float w1s[192];
    __shared__ float As[16], Cs[16];
    int tid = threadIdx.x;
    if (tid < 192) w1s[tid] = w[tid];
    if (tid < 16) {
        float s = g[tid] / sqrtf(v[tid] + 1e-5f);
        As[tid] = s;
        Cs[tid] = (cb[tid] - m[tid]) * s + bb[tid];
    }
    __syncthreads();

    int gid = blockIdx.x * 256 + tid;
    int b   = gid >> 12;
    int rem = gid & 4095;
    int oi  = rem >> 6, oj = rem & 63;

    float xr[3][4][4];
    #pragma unroll
    for (int ci = 0; ci < 3; ++ci) {
        #pragma unroll
        for (int r = 0; r < 4; ++r) {
            const float4 t4 = *(const float4*)(x +
                (((size_t)(b * 3 + ci) * 256 + (4 * oi + r)) * 256 + 4 * oj));
            xr[ci][r][0] = t4.x; xr[ci][r][1] = t4.y;
            xr[ci][r][2] = t4.z; xr[ci][r][3] = t4.w;
        }
    }
    const float4* w4 = (const float4*)w1s;
    #pragma unroll
    for (int co = 0; co < 16; ++co) {
        float val[2][2] = {{0.f, 0.f}, {0.f, 0.f}};
        #pragma unroll
        for (int ci = 0; ci < 3; ++ci) {
            float4 wq = w4[co * 3 + ci];
            #pragma unroll
            for (int pi = 0; pi < 2; ++pi) {
                #pragma unroll
                for (int pj = 0; pj < 2; ++pj) {
                    float a = val[pi][pj];
                    a = fmaf(xr[ci][2*pi  ][2*pj  ], wq.x, a);
                    a = fmaf(xr[ci][2*pi  ][2*pj+1], wq.y, a);
                    a = fmaf(xr[ci][2*pi+1][2*pj  ], wq.z, a);
                    a = fmaf(xr[ci][2*pi+1][2*pj+1], wq.w, a);
                    val[pi][pj] = a;
                }
            }
        }
        float A = As[co], C = Cs[co];
        float mx = 0.0f;
        #pragma unroll
        for (int pi = 0; pi < 2; ++pi)
            #pragma unroll
            for (int pj = 0; pj < 2; ++pj)
                mx = fmaxf(mx, fmaf(A, val[pi][pj], C));
        c1[((size_t)(b * 16 + co) * 64 + oi) * 64 + oj] = mx;
    }
}

// ---------------- Kernel 2: conv2 + bn2 + relu + maxpool2 -> c (64,256)
__global__ __launch_bounds__(256) void k_conv2(
    const float* __restrict__ c1, const float* __restrict__ w2,
    const float* __restrict__ cb, const float* __restrict__ g,
    const float* __restrict__ bb, const float* __restrict__ m,
    const float* __restrict__ v, float* __restrict__ c)
{
    __shared__ float w2s[64];
    int tid = threadIdx.x;
    if (tid < 64) w2s[tid] = w2[tid];
    __syncthreads();
    float A2 = g[0] / sqrtf(v[0] + 1e-5f);
    float C2 = (cb[0] - m[0]) * A2 + bb[0];

    int gid = blockIdx.x * 256 + tid;
    int b   = gid >> 8;
    int rem = gid & 255;
    int oi  = rem >> 4, oj = rem & 15;

    float val[2][2] = {{0.f, 0.f}, {0.f, 0.f}};
    for (int ci = 0; ci < 16; ++ci) {
        float xr[4][4];
        #pragma unroll
        for (int r = 0; r < 4; ++r) {
            float4 t4 = *(const float4*)(c1 +
                (((size_t)(b * 16 + ci) * 64 + (4 * oi + r)) * 64 + 4 * oj));
            xr[r][0] = t4.x; xr[r][1] = t4.y; xr[r][2] = t4.z; xr[r][3] = t4.w;
        }
        float w0 = w2s[ci*4+0], w1 = w2s[ci*4+1], w2v = w2s[ci*4+2], w3 = w2s[ci*4+3];
        #pragma unroll
        for (int pi = 0; pi < 2; ++pi) {
            #pragma unroll
            for (int pj = 0; pj < 2; ++pj) {
                float a = val[pi][pj];
                a = fmaf(xr[2*pi  ][2*pj  ], w0, a);
                a = fmaf(xr[2*pi  ][2*pj+1], w1, a);
                a = fmaf(xr[2*pi+1][2*pj  ], w2v, a);
                a = fmaf(xr[2*pi+1][2*pj+1], w3, a);
                val[pi][pj] = a;
            }
        }
    }
    float mx = 0.0f;
    #pragma unroll
    for (int pi = 0; pi < 2; ++pi)
        #pragma unroll
        for (int pj = 0; pj < 2; ++pj)
            mx = fmaxf(mx, fmaf(A2, val[pi][pj], C2));
    c[(size_t)b * 256 + oi * 16 + oj] = mx;
}

// ---------------- Kernel 3: MLP + softmax -> S (64,8) row-major flat
__global__ __launch_bounds__(64) void k_mlp(
    const float* __restrict__ c,
    const float* __restrict__ w1, const float* __restrict__ b1,
    const float* __restrict__ w2, const float* __restrict__ b2,
    const float* __restrict__ w3, const float* __restrict__ b3,
    float* __restrict__ S)
{
    __shared__ __align__(16) float cs[256];
    __shared__ float h1s[32], h2s[32], ls[8];
    int b = blockIdx.x, tid = threadIdx.x;
    *(float4*)&cs[tid * 4] = *(const float4*)(c + (size_t)b * 256 + tid * 4);
    __syncthreads();
    if (tid < 32) {
        float acc = b1[tid];
        for (int k = 0; k < 256; ++k) acc = fmaf(cs[k], w1[tid * 256 + k], acc);
        h1s[tid] = fmaxf(acc, 0.f);
    }
    __syncthreads();
    if (tid < 32) {
        float acc = b2[tid];
        #pragma unroll
        for (int k = 0; k < 32; ++k) acc = fmaf(h1s[k], w2[tid * 32 + k], acc);
        h2s[tid] = fmaxf(acc, 0.f);
    }
    __syncthreads();
    if (tid < 8) {
        float acc = b3[tid];
        #pragma unroll
        for (int k = 0; k < 32; ++k) acc = fmaf(h2s[k], w3[tid * 32 + k], acc);
        ls[tid] = acc;
    }
    __syncthreads();
    if (tid == 0) {
        float mx = ls[0];
        #pragma unroll
        for (int k = 1; k < 8; ++k) mx = fmaxf(mx, ls[k]);
        float e[8]; float sum = 0.f;
        #pragma unroll
        for (int k = 0; k < 8; ++k) { e[k] = expf(ls[k] - mx); sum += e[k]; }
        float inv = 1.0f / sum;
        #pragma unroll
        for (int k = 0; k < 8; ++k) S[b * 8 + k] = e[k] * inv;
    }
}

// ---------------- Kernel 4: LSTM, 256 steps.
// Block = (class, 2 batch rows), 1024 threads.
// Thread (g = tid>>1, kh = tid&1) owns whh[g][kh*64 .. kh*64+63] in 16 float4
// registers; lane pair tid^1 combines partial dots via shfl_xor.
__global__ __launch_bounds__(1024, 4) void k_lstm(
    const float* __restrict__ whh, const float* __restrict__ wih,
    const float* __restrict__ bih, const float* __restrict__ bhh,
    const float* __restrict__ hn,  const float* __restrict__ c,
    float* __restrict__ lasth)
{
    __shared__ __align__(16) float h_lds[2][128];
    __shared__ float g_lds[2][512];
    __shared__ __align__(16) float c_lds[2][256];

    int tid   = threadIdx.x;
    int g     = tid >> 1;     // gate row 0..511
    int kh    = tid & 1;      // which half of the 128-dot
    int kcls  = blockIdx.x >> 5;
    int bbase = (blockIdx.x & 31) * 2;

    // 64 weights (16 float4) per thread — register-resident
    float4 w[16];
    {
        const float4* wp = (const float4*)(whh +
            ((size_t)(kcls * 512 + g)) * 128 + kh * 64);
        #pragma unroll
        for (int i = 0; i < 16; ++i) w[i] = wp[i];
    }
    float xw   = wih[kcls * 512 + g];
    float bias = bih[kcls * 512 + g] + bhh[kcls * 512 + g];

    if (tid < 256) {
        int b = tid >> 7, j = tid & 127;
        h_lds[b][j] = hn[((size_t)kcls * 64 + bbase + b) * 128 + j];
    }
    if (tid < 128) {
        int f = tid * 4; int b = f >> 8; int off = f & 255;
        *(float4*)&c_lds[b][off] = *(const float4*)(c + (size_t)(bbase + b) * 256 + off);
    }
    float cc = 0.0f;
    __syncthreads();

    const float* hb0 = &h_lds[0][kh * 64];
    const float* hb1 = &h_lds[1][kh * 64];

    for (int t = 0; t < 256; ++t) {
        float ct0 = c_lds[0][t], ct1 = c_lds[1][t];
        // bias + x*wih contributed by the kh==0 partial only
        float a0 = kh ? 0.0f : fmaf(ct0, xw, bias);
        float a1 = kh ? 0.0f : fmaf(ct1, xw, bias);
        float p0 = 0.0f, p1 = 0.0f;  // second dependency chains
        #pragma unroll
        for (int i = 0; i < 16; i += 2) {
            float4 h0  = *(const float4*)&hb0[4 * i];
            float4 h1  = *(const float4*)&hb1[4 * i];
            float4 h0b = *(const float4*)&hb0[4 * i + 4];
            float4 h1b = *(const float4*)&hb1[4 * i + 4];
            float4 wa = w[i], wb = w[i + 1];
            a0 = fmaf(wa.x, h0.x, a0);  a1 = fmaf(wa.x, h1.x, a1);
            a0 = fmaf(wa.y, h0.y, a0);  a1 = fmaf(wa.y, h1.y, a1);
            a0 = fmaf(wa.z, h0.z, a0);  a1 = fmaf(wa.z, h1.z, a1);
            a0 = fmaf(wa.w, h0.w, a0);  a1 = fmaf(wa.w, h1.w, a1);
            p0 = fmaf(wb.x, h0b.x, p0); p1 = fmaf(wb.x, h1b.x, p1);
            p0 = fmaf(wb.y, h0b.y, p0); p1 = fmaf(wb.y, h1b.y, p1);
            p0 = fmaf(wb.z, h0b.z, p0); p1 = fmaf(wb.z, h1b.z, p1);
            p0 = fmaf(wb.w, h0b.w, p0); p1 = fmaf(wb.w, h1b.w, p1);
        }
        a0 += p0; a1 += p1;
        a0 += __shfl_xor(a0, 1);   // both lanes now hold full row-0 gate
        a1 += __shfl_xor(a1, 1);   // both lanes now hold full row-1 gate
        g_lds[kh][g] = kh ? a1 : a0;  // even lane -> row0, odd lane -> row1
        __syncthreads();

        if (tid < 256) {
            int b = tid >> 7, j = tid & 127;
            float gi = sigmoidf_(g_lds[b][j]);
            float gf = sigmoidf_(g_lds[b][128 + j]);
            float gg = tanhf_(g_lds[b][256 + j]);
            float go = sigmoidf_(g_lds[b][384 + j]);
            cc = gf * cc + gi * gg;
            float h = go * tanhf_(cc);
            h_lds[b][j] = h;
            if (j == 127)
                lasth[((size_t)kcls * 64 + bbase + b) * 256 + t] = h;
        }
        __syncthreads();
    }
}

// ---------------- Kernel 5: gated mean over classes + output projection
__global__ __launch_bounds__(256) void k_out(
    const float* __restrict__ lasth, const float* __restrict__ S,
    const float* __restrict__ out_w, const float* __restrict__ out_b,
    float* __restrict__ out)
{
    __shared__ __align__(16) float avg[256];
    int b = blockIdx.x, t = threadIdx.x;
    float a = 0.f;
    #pragma unroll
    for (int k = 0; k < 8; ++k) {
        // pre.reshape(NCLS,B,1): weight(k,b) = S_flat[k*64+b]
        a = fmaf(S[k * 64 + b], lasth[((size_t)k * 64 + b) * 256 + t], a);
    }
    avg[t] = a * 0.125f;
    __syncthreads();
    if (t < 8) {
        float acc = out_b[t];
        for (int tt = 0; tt < 256; ++tt)
            acc = fmaf(avg[tt], out_w[t * 256 + tt], acc);
        out[b * 8 + t] = acc;
    }
}

extern "C" void kernel_launch(void* const* d_in, const int* in_sizes, int n_in,
                              void* d_out, int out_size, void* d_ws, size_t ws_size,
                              hipStream_t stream) {
    const float* x       = (const float*)d_in[0];
    const float* conv1_w = (const float*)d_in[1];
    const float* conv1_b = (const float*)d_in[2];
    const float* bn1_g   = (const float*)d_in[3];
    const float* bn1_b   = (const float*)d_in[4];
    const float* bn1_m   = (const float*)d_in[5];
    const float* bn1_v   = (const float*)d_in[6];
    const float* conv2_w = (const float*)d_in[7];
    const float* conv2_b = (const float*)d_in[8];
    const float* bn2_g   = (const float*)d_in[9];
    const float* bn2_b   = (const float*)d_in[10];
    const float* bn2_m   = (const float*)d_in[11];
    const float* bn2_v   = (const float*)d_in[12];
    const float* pre_w1  = (const float*)d_in[13];
    const float* pre_b1  = (const float*)d_in[14];
    const float* pre_w2  = (const float*)d_in[15];
    const float* pre_b2  = (const float*)d_in[16];
    const float* pre_w3  = (const float*)d_in[17];
    const float* pre_b3  = (const float*)d_in[18];
    const float* lstm_wih = (const float*)d_in[19];
    const float* lstm_whh = (const float*)d_in[20];
    const float* lstm_bih = (const float*)d_in[21];
    const float* lstm_bhh = (const float*)d_in[22];
    const float* hn      = (const float*)d_in[23];
    const float* out_w   = (const float*)d_in[24];
    const float* out_b   = (const float*)d_in[25];

    float* ws    = (float*)d_ws;
    float* c1    = ws;                       // 64*16*64*64 = 4194304
    float* c     = c1 + 4194304;             // 64*256      = 16384
    float* S     = c + 16384;                // 64*8        = 512
    float* lasth = S + 512;                  // 8*64*256    = 131072

    k_conv1<<<1024, 256, 0, stream>>>(x, conv1_w, conv1_b, bn1_g, bn1_b, bn1_m, bn1_v, c1);
    k_conv2<<<64, 256, 0, stream>>>(c1, conv2_w, conv2_b, bn2_g, bn2_b, bn2_m, bn2_v, c);
    k_mlp<<<64, 64, 0, stream>>>(c, pre_w1, pre_b1, pre_w2, pre_b2, pre_w3, pre_b3, S);
    k_lstm<<<256, 1024, 0, stream>>>(lstm_whh, lstm_wih, lstm_bih, lstm_bhh, hn, c, lasth);
    k_out<<<64, 256, 0, stream>>>(lasth, S, out_w, out_b, (float*)d_out);
}

// Round 3
// 404.184 us; speedup vs baseline: 1.8753x; 1.8753x over previous
//
#include <hip/hip_runtime.h>
#include <hip/hip_bf16.h>

// NeuralNetwork_85255100825763
// conv1+bn+relu+pool -> conv2+bn+relu+pool -> MLP+softmax gate
// -> 8x LSTM(128) over 256 steps -> gated mean -> output proj.
// LSTM v3: 256 blocks x 512 threads (1 block/CU). Thread owns a FULL
// 128-float gate row held in 32 NAMED float4 registers (no array ->
// no scratch; amdgpu_waves_per_eu(2,2) gives a 256-VGPR budget so the
// compiler has no occupancy incentive to spill). h reads are all-lane
// broadcast ds_read_b128 (zero bank conflicts). 2 barriers/step.

__device__ __forceinline__ float sigmoidf_(float x) {
    return 1.0f / (1.0f + __expf(-x));
}
__device__ __forceinline__ float tanhf_(float x) {
    float t = __expf(-2.0f * fabsf(x));   // in (0,1], no overflow
    float r = (1.0f - t) / (1.0f + t);
    return copysignf(r, x);
}

// ---------------- Kernel 1: conv1 + bn1 + relu + maxpool2 -> c1 (64,16,64,64)
__global__ __launch_bounds__(256) void k_conv1(
    const float* __restrict__ x, const float* __restrict__ w,
    const float* __restrict__ cb, const float* __restrict__ g,
    const float* __restrict__ bb, const float* __restrict__ m,
    const float* __restrict__ v, float* __restrict__ c1)
{
    __shared__ __align__(16) float w1s[192];
    __shared__ float As[16], Cs[16];
    int tid = threadIdx.x;
    if (tid < 192) w1s[tid] = w[tid];
    if (tid < 16) {
        float s = g[tid] / sqrtf(v[tid] + 1e-5f);
        As[tid] = s;
        Cs[tid] = (cb[tid] - m[tid]) * s + bb[tid];
    }
    __syncthreads();

    int gid = blockIdx.x * 256 + tid;
    int b   = gid >> 12;
    int rem = gid & 4095;
    int oi  = rem >> 6, oj = rem & 63;

    float xr[3][4][4];
    #pragma unroll
    for (int ci = 0; ci < 3; ++ci) {
        #pragma unroll
        for (int r = 0; r < 4; ++r) {
            const float4 t4 = *(const float4*)(x +
                (((size_t)(b * 3 + ci) * 256 + (4 * oi + r)) * 256 + 4 * oj));
            xr[ci][r][0] = t4.x; xr[ci][r][1] = t4.y;
            xr[ci][r][2] = t4.z; xr[ci][r][3] = t4.w;
        }
    }
    const float4* w4 = (const float4*)w1s;
    #pragma unroll
    for (int co = 0; co < 16; ++co) {
        float val[2][2] = {{0.f, 0.f}, {0.f, 0.f}};
        #pragma unroll
        for (int ci = 0; ci < 3; ++ci) {
            float4 wq = w4[co * 3 + ci];
            #pragma unroll
            for (int pi = 0; pi < 2; ++pi) {
                #pragma unroll
                for (int pj = 0; pj < 2; ++pj) {
                    float a = val[pi][pj];
                    a = fmaf(xr[ci][2*pi  ][2*pj  ], wq.x, a);
                    a = fmaf(xr[ci][2*pi  ][2*pj+1], wq.y, a);
                    a = fmaf(xr[ci][2*pi+1][2*pj  ], wq.z, a);
                    a = fmaf(xr[ci][2*pi+1][2*pj+1], wq.w, a);
                    val[pi][pj] = a;
                }
            }
        }
        float A = As[co], C = Cs[co];
        float mx = 0.0f;
        #pragma unroll
        for (int pi = 0; pi < 2; ++pi)
            #pragma unroll
            for (int pj = 0; pj < 2; ++pj)
                mx = fmaxf(mx, fmaf(A, val[pi][pj], C));
        c1[((size_t)(b * 16 + co) * 64 + oi) * 64 + oj] = mx;
    }
}

// ---------------- Kernel 2: conv2 + bn2 + relu + maxpool2 -> c (64,256)
__global__ __launch_bounds__(256) void k_conv2(
    const float* __restrict__ c1, const float* __restrict__ w2,
    const float* __restrict__ cb, const float* __restrict__ g,
    const float* __restrict__ bb, const float* __restrict__ m,
    const float* __restrict__ v, float* __restrict__ c)
{
    __shared__ float w2s[64];
    int tid = threadIdx.x;
    if (tid < 64) w2s[tid] = w2[tid];
    __syncthreads();
    float A2 = g[0] / sqrtf(v[0] + 1e-5f);
    float C2 = (cb[0] - m[0]) * A2 + bb[0];

    int gid = blockIdx.x * 256 + tid;
    int b   = gid >> 8;
    int rem = gid & 255;
    int oi  = rem >> 4, oj = rem & 15;

    float val[2][2] = {{0.f, 0.f}, {0.f, 0.f}};
    for (int ci = 0; ci < 16; ++ci) {
        float xr[4][4];
        #pragma unroll
        for (int r = 0; r < 4; ++r) {
            float4 t4 = *(const float4*)(c1 +
                (((size_t)(b * 16 + ci) * 64 + (4 * oi + r)) * 64 + 4 * oj));
            xr[r][0] = t4.x; xr[r][1] = t4.y; xr[r][2] = t4.z; xr[r][3] = t4.w;
        }
        float w0 = w2s[ci*4+0], w1 = w2s[ci*4+1], w2v = w2s[ci*4+2], w3 = w2s[ci*4+3];
        #pragma unroll
        for (int pi = 0; pi < 2; ++pi) {
            #pragma unroll
            for (int pj = 0; pj < 2; ++pj) {
                float a = val[pi][pj];
                a = fmaf(xr[2*pi  ][2*pj  ], w0, a);
                a = fmaf(xr[2*pi  ][2*pj+1], w1, a);
                a = fmaf(xr[2*pi+1][2*pj  ], w2v, a);
                a = fmaf(xr[2*pi+1][2*pj+1], w3, a);
                val[pi][pj] = a;
            }
        }
    }
    float mx = 0.0f;
    #pragma unroll
    for (int pi = 0; pi < 2; ++pi)
        #pragma unroll
        for (int pj = 0; pj < 2; ++pj)
            mx = fmaxf(mx, fmaf(A2, val[pi][pj], C2));
    c[(size_t)b * 256 + oi * 16 + oj] = mx;
}

// ---------------- Kernel 3: MLP + softmax -> S (64,8) row-major flat
__global__ __launch_bounds__(64) void k_mlp(
    const float* __restrict__ c,
    const float* __restrict__ w1, const float* __restrict__ b1,
    const float* __restrict__ w2, const float* __restrict__ b2,
    const float* __restrict__ w3, const float* __restrict__ b3,
    float* __restrict__ S)
{
    __shared__ __align__(16) float cs[256];
    __shared__ float h1s[32], h2s[32], ls[8];
    int b = blockIdx.x, tid = threadIdx.x;
    *(float4*)&cs[tid * 4] = *(const float4*)(c + (size_t)b * 256 + tid * 4);
    __syncthreads();
    if (tid < 32) {
        float acc = b1[tid];
        for (int k = 0; k < 256; ++k) acc = fmaf(cs[k], w1[tid * 256 + k], acc);
        h1s[tid] = fmaxf(acc, 0.f);
    }
    __syncthreads();
    if (tid < 32) {
        float acc = b2[tid];
        #pragma unroll
        for (int k = 0; k < 32; ++k) acc = fmaf(h1s[k], w2[tid * 32 + k], acc);
        h2s[tid] = fmaxf(acc, 0.f);
    }
    __syncthreads();
    if (tid < 8) {
        float acc = b3[tid];
        #pragma unroll
        for (int k = 0; k < 32; ++k) acc = fmaf(h2s[k], w3[tid * 32 + k], acc);
        ls[tid] = acc;
    }
    __syncthreads();
    if (tid == 0) {
        float mx = ls[0];
        #pragma unroll
        for (int k = 1; k < 8; ++k) mx = fmaxf(mx, ls[k]);
        float e[8]; float sum = 0.f;
        #pragma unroll
        for (int k = 0; k < 8; ++k) { e[k] = expf(ls[k] - mx); sum += e[k]; }
        float inv = 1.0f / sum;
        #pragma unroll
        for (int k = 0; k < 8; ++k) S[b * 8 + k] = e[k] * inv;
    }
}

// ---------------- Kernel 4: LSTM, 256 steps. Block = (class, 2 batch rows).
// Thread g owns whh[g][0..127] in 32 NAMED float4 registers.
__global__ __launch_bounds__(512)
__attribute__((amdgpu_waves_per_eu(2, 2)))
void k_lstm(
    const float* __restrict__ whh, const float* __restrict__ wih,
    const float* __restrict__ bih, const float* __restrict__ bhh,
    const float* __restrict__ hn,  const float* __restrict__ c,
    float* __restrict__ lasth)
{
    __shared__ __align__(16) float h_lds[2][128];
    __shared__ float g_lds[2][512];
    __shared__ __align__(16) float c_lds[2][256];

    int tid   = threadIdx.x;
    int kcls  = blockIdx.x >> 5;
    int bbase = (blockIdx.x & 31) * 2;

    const float4* wp = (const float4*)(whh + ((size_t)(kcls * 512 + tid)) * 128);
    float4 wv0  = wp[0],  wv1  = wp[1],  wv2  = wp[2],  wv3  = wp[3];
    float4 wv4  = wp[4],  wv5  = wp[5],  wv6  = wp[6],  wv7  = wp[7];
    float4 wv8  = wp[8],  wv9  = wp[9],  wv10 = wp[10], wv11 = wp[11];
    float4 wv12 = wp[12], wv13 = wp[13], wv14 = wp[14], wv15 = wp[15];
    float4 wv16 = wp[16], wv17 = wp[17], wv18 = wp[18], wv19 = wp[19];
    float4 wv20 = wp[20], wv21 = wp[21], wv22 = wp[22], wv23 = wp[23];
    float4 wv24 = wp[24], wv25 = wp[25], wv26 = wp[26], wv27 = wp[27];
    float4 wv28 = wp[28], wv29 = wp[29], wv30 = wp[30], wv31 = wp[31];

    float xw   = wih[kcls * 512 + tid];
    float bias = bih[kcls * 512 + tid] + bhh[kcls * 512 + tid];

    if (tid < 256) {
        int b = tid >> 7, j = tid & 127;
        h_lds[b][j] = hn[((size_t)kcls * 64 + bbase + b) * 128 + j];
    }
    if (tid < 128) {
        int f = tid * 4; int b = f >> 8; int off = f & 255;
        *(float4*)&c_lds[b][off] = *(const float4*)(c + (size_t)(bbase + b) * 256 + off);
    }
    float cc = 0.0f;
    __syncthreads();

// one float4 weight group: rows 0/1 broadcast-read, alternating acc chains
#define WSTEP(I, A0, A1)                                            \
    {                                                               \
        float4 h0 = *(const float4*)&h_lds[0][4 * (I)];             \
        float4 h1 = *(const float4*)&h_lds[1][4 * (I)];             \
        A0 = fmaf(wv##I.x, h0.x, A0); A1 = fmaf(wv##I.x, h1.x, A1); \
        A0 = fmaf(wv##I.y, h0.y, A0); A1 = fmaf(wv##I.y, h1.y, A1); \
        A0 = fmaf(wv##I.z, h0.z, A0); A1 = fmaf(wv##I.z, h1.z, A1); \
        A0 = fmaf(wv##I.w, h0.w, A0); A1 = fmaf(wv##I.w, h1.w, A1); \
    }

    for (int t = 0; t < 256; ++t) {
        float a0 = fmaf(c_lds[0][t], xw, bias);
        float a1 = fmaf(c_lds[1][t], xw, bias);
        float b0 = 0.0f, b1 = 0.0f;   // second pair of dep chains
        WSTEP(0,  a0, a1) WSTEP(1,  b0, b1) WSTEP(2,  a0, a1) WSTEP(3,  b0, b1)
        WSTEP(4,  a0, a1) WSTEP(5,  b0, b1) WSTEP(6,  a0, a1) WSTEP(7,  b0, b1)
        WSTEP(8,  a0, a1) WSTEP(9,  b0, b1) WSTEP(10, a0, a1) WSTEP(11, b0, b1)
        WSTEP(12, a0, a1) WSTEP(13, b0, b1) WSTEP(14, a0, a1) WSTEP(15, b0, b1)
        WSTEP(16, a0, a1) WSTEP(17, b0, b1) WSTEP(18, a0, a1) WSTEP(19, b0, b1)
        WSTEP(20, a0, a1) WSTEP(21, b0, b1) WSTEP(22, a0, a1) WSTEP(23, b0, b1)
        WSTEP(24, a0, a1) WSTEP(25, b0, b1) WSTEP(26, a0, a1) WSTEP(27, b0, b1)
        WSTEP(28, a0, a1) WSTEP(29, b0, b1) WSTEP(30, a0, a1) WSTEP(31, b0, b1)
        g_lds[0][tid] = a0 + b0;
        g_lds[1][tid] = a1 + b1;
        __syncthreads();   // gates visible; all h reads done

        if (tid < 256) {
            int b = tid >> 7, j = tid & 127;
            float gi = sigmoidf_(g_lds[b][j]);
            float gf = sigmoidf_(g_lds[b][128 + j]);
            float gg = tanhf_(g_lds[b][256 + j]);
            float go = sigmoidf_(g_lds[b][384 + j]);
            cc = gf * cc + gi * gg;
            float h = go * tanhf_(cc);
            h_lds[b][j] = h;
            if (j == 127)
                lasth[((size_t)kcls * 64 + bbase + b) * 256 + t] = h;
        }
        __syncthreads();   // new h visible
    }
#undef WSTEP
}

// ---------------- Kernel 5: gated mean over classes + output projection
__global__ __launch_bounds__(256) void k_out(
    const float* __restrict__ lasth, const float* __restrict__ S,
    const float* __restrict__ out_w, const float* __restrict__ out_b,
    float* __restrict__ out)
{
    __shared__ __align__(16) float avg[256];
    int b = blockIdx.x, t = threadIdx.x;
    float a = 0.f;
    #pragma unroll
    for (int k = 0; k < 8; ++k) {
        // pre.reshape(NCLS,B,1): weight(k,b) = S_flat[k*64+b]
        a = fmaf(S[k * 64 + b], lasth[((size_t)k * 64 + b) * 256 + t], a);
    }
    avg[t] = a * 0.125f;
    __syncthreads();
    if (t < 8) {
        float acc = out_b[t];
        for (int tt = 0; tt < 256; ++tt)
            acc = fmaf(avg[tt], out_w[t * 256 + tt], acc);
        out[b * 8 + t] = acc;
    }
}

extern "C" void kernel_launch(void* const* d_in, const int* in_sizes, int n_in,
                              void* d_out, int out_size, void* d_ws, size_t ws_size,
                              hipStream_t stream) {
    const float* x       = (const float*)d_in[0];
    const float* conv1_w = (const float*)d_in[1];
    const float* conv1_b = (const float*)d_in[2];
    const float* bn1_g   = (const float*)d_in[3];
    const float* bn1_b   = (const float*)d_in[4];
    const float* bn1_m   = (const float*)d_in[5];
    const float* bn1_v   = (const float*)d_in[6];
    const float* conv2_w = (const float*)d_in[7];
    const float* conv2_b = (const float*)d_in[8];
    const float* bn2_g   = (const float*)d_in[9];
    const float* bn2_b   = (const float*)d_in[10];
    const float* bn2_m   = (const float*)d_in[11];
    const float* bn2_v   = (const float*)d_in[12];
    const float* pre_w1  = (const float*)d_in[13];
    const float* pre_b1  = (const float*)d_in[14];
    const float* pre_w2  = (const float*)d_in[15];
    const float* pre_b2  = (const float*)d_in[16];
    const float* pre_w3  = (const float*)d_in[17];
    const float* pre_b3  = (const float*)d_in[18];
    const float* lstm_wih = (const float*)d_in[19];
    const float* lstm_whh = (const float*)d_in[20];
    const float* lstm_bih = (const float*)d_in[21];
    const float* lstm_bhh = (const float*)d_in[22];
    const float* hn      = (const float*)d_in[23];
    const float* out_w   = (const float*)d_in[24];
    const float* out_b   = (const float*)d_in[25];

    float* ws    = (float*)d_ws;
    float* c1    = ws;                       // 64*16*64*64 = 4194304
    float* c     = c1 + 4194304;             // 64*256      = 16384
    float* S     = c + 16384;                // 64*8        = 512
    float* lasth = S + 512;                  // 8*64*256    = 131072

    k_conv1<<<1024, 256, 0, stream>>>(x, conv1_w, conv1_b, bn1_g, bn1_b, bn1_m, bn1_v, c1);
    k_conv2<<<64, 256, 0, stream>>>(c1, conv2_w, conv2_b, bn2_g, bn2_b, bn2_m, bn2_v, c);
    k_mlp<<<64, 64, 0, stream>>>(c, pre_w1, pre_b1, pre_w2, pre_b2, pre_w3, pre_b3, S);
    k_lstm<<<256, 512, 0, stream>>>(lstm_whh, lstm_wih, lstm_bih, lstm_bhh, hn, c, lasth);
    k_out<<<64, 256, 0, stream>>>(lasth, S, out_w, out_b, (float*)d_out);
}